// Round 13
// baseline (157.551 us; speedup 1.0000x reference)
//
#include <hip/hip_runtime.h>
#include <cstdint>

// Chamfer distance, B=8, N=M=4096, D=128, f32 in, scalar f32 out.
// R13: barrier-free dataflow. R8-R12 all plateau at ~47-56us regardless of
// occupancy geometry -> the per-tile __syncthreads+DMA-drain convoy is the
// limiter, not wave supply. Now: NO LDS staging of B, no per-tile barriers.
// Each wave reads B-frags (16B/lane) straight from global (L1/L2-resident:
// unique y-slice/batch ~1MB; restream 512MB ~15us at L2 rate, overlapped
// with 16.6us MFMA). A in registers. Col-min via 2 shfl + LDS atomicMin
// (2KB cminS, banks distinct); 2 barriers per block total.
// Workspace: xb(8M) yb(8M) x2(128K) y2(128K) rowpart(1M) colpart(2M).

#define B_   8
#define N_   4096
#define M_   4096
#define D_   128
#define TPB  8               // y-tiles (64 cols) per block -> 512-col chunk
#define ROWS_PB 256          // x-rows per block = 4 waves * 64
#define XG   (N_ / ROWS_PB)  // 16 x-groups
#define CHUNKS (M_ / (TPB * 64))   // 8 y-chunks

typedef __bf16 bf16x8 __attribute__((ext_vector_type(8)));
typedef float  f32x4  __attribute__((ext_vector_type(4)));
typedef unsigned int u32;

static __device__ __forceinline__ unsigned short f2bf(float f) {
  unsigned u = __float_as_uint(f);
  u += 0x7FFFu + ((u >> 16) & 1u);   // round-to-nearest-even
  return (unsigned short)(u >> 16);
}

// Pass 1: wave handles 2 rows (32 lanes x float4 each). xb = bf16(-2x),
// yb = bf16(y), fp32 norms.
__global__ __launch_bounds__(256) void pass1_prep(
    const float* __restrict__ x, const float* __restrict__ y,
    unsigned short* __restrict__ xb, unsigned short* __restrict__ yb,
    float* __restrict__ x2, float* __restrict__ y2)
{
  const int ROWS = B_ * N_;
  int gw   = (blockIdx.x * 256 + threadIdx.x) >> 6;   // wave id
  int lane = threadIdx.x & 63;
  int half = lane >> 5, sub = lane & 31;
  int row2 = gw * 2 + half;                  // 0 .. 2*ROWS-1 (x rows then y rows)
  bool isx = row2 < ROWS;
  const float* src; unsigned short* dst; float* nrm; int row;
  if (isx) { src = x; dst = xb; nrm = x2; row = row2; }
  else     { src = y; dst = yb; nrm = y2; row = row2 - ROWS; }
  size_t base = (size_t)row * D_ + sub * 4;
  float4 v = *(const float4*)(src + base);
  float sx = isx ? -2.0f : 1.0f;
  u32 p0 = (u32)f2bf(sx * v.x) | ((u32)f2bf(sx * v.y) << 16);
  u32 p1 = (u32)f2bf(sx * v.z) | ((u32)f2bf(sx * v.w) << 16);
  *(uint2*)(dst + base) = make_uint2(p0, p1);
  float s = v.x * v.x + v.y * v.y + v.z * v.z + v.w * v.w;
  #pragma unroll
  for (int m = 1; m < 32; m <<= 1) s += __shfl_xor(s, m, 64);
  if (sub == 0) nrm[row] = s;
}

// Pass 2: block = 256 x-rows (4 waves x 64 rows = 4 row-tiles of 16), loops
// over TPB y-tiles of 64 cols, B-fragments read DIRECTLY from global
// (L1/L2). Fragment layouts (HW-verified):
//   A/B operand: lane holds elems [row=lane&15][k=(lane>>4)*8 + 0..7]
//   C/D:         lane reg r holds [row=(lane>>4)*4+r][col=lane&15]
// acc init = x2_i, so final a = x2_i - 2<x,y>; s = a + y2_j = d^2.
// No hot-loop barriers: col-min = 2 shfl + LDS atomicMin into cminS.
__global__ __launch_bounds__(256) void pass2_tile(
    const unsigned short* __restrict__ xb, const unsigned short* __restrict__ yb,
    const float* __restrict__ x2, const float* __restrict__ y2,
    float* __restrict__ rowpart, float* __restrict__ colpart)
{
  __shared__ u32 cminS[TPB * 64];   // 512 cols, d^2 bits (2 KB)

  const int tid  = threadIdx.x;
  const int wave = tid >> 6;                 // 0..3
  const int lane = tid & 63;
  const int quad = lane >> 4;
  const int l15  = lane & 15;

  const int id    = blockIdx.x;        // 0..1023
  const int b     = id & 7;
  const int xg    = (id >> 3) & 15;
  const int chunk = id >> 7;           // 0..7
  const int n0    = xg * ROWS_PB;
  const int mc0   = chunk * (TPB * 64);

  cminS[tid]       = 0x7F800000u;
  cminS[tid + 256] = 0x7F800000u;

  // A fragments: direct global->register, rows n0 + wave*64 + rt*16 + l15.
  bf16x8 afrag[4][4];   // [kb][rt] : 64 VGPRs
  const size_t xrow0 = (size_t)b * N_ + n0 + wave * 64;
  #pragma unroll
  for (int kb = 0; kb < 4; ++kb)
    #pragma unroll
    for (int rt = 0; rt < 4; ++rt)
      afrag[kb][rt] = *(const bf16x8*)(xb + (xrow0 + rt * 16 + l15) * D_ + kb * 32 + quad * 8);

  // x2 for this wave's 16 output rows (t-invariant), as f32x4 for acc init
  f32x4 xvv[4];
  #pragma unroll
  for (int rt = 0; rt < 4; ++rt)
    #pragma unroll
    for (int r = 0; r < 4; ++r)
      xvv[rt][r] = x2[(size_t)b * N_ + n0 + wave * 64 + rt * 16 + quad * 4 + r];

  const float FINF = __uint_as_float(0x7F800000u);
  float rmin2[4][4];
  #pragma unroll
  for (int rt = 0; rt < 4; ++rt)
    #pragma unroll
    for (int r = 0; r < 4; ++r) rmin2[rt][r] = FINF;

  __syncthreads();   // cminS init visible

  const unsigned short* ybch = yb + ((size_t)b * M_ + mc0) * D_;  // chunk base
  const float*          y2ch = y2 + (size_t)b * M_ + mc0;

  #pragma unroll 1
  for (int t = 0; t < TPB; ++t) {
    const int c0 = t * 64;   // col offset within chunk

    #pragma unroll
    for (int ct = 0; ct < 4; ++ct) {
      const int col = c0 + ct * 16 + l15;     // this lane's B row (= y col)
      float yv = y2ch[col];
      // 4 independent 16B loads (pipelined by compiler via vmcnt)
      bf16x8 bfr0 = *(const bf16x8*)(ybch + (size_t)col * D_ + 0 * 32 + quad * 8);
      bf16x8 bfr1 = *(const bf16x8*)(ybch + (size_t)col * D_ + 1 * 32 + quad * 8);
      bf16x8 bfr2 = *(const bf16x8*)(ybch + (size_t)col * D_ + 2 * 32 + quad * 8);
      bf16x8 bfr3 = *(const bf16x8*)(ybch + (size_t)col * D_ + 3 * 32 + quad * 8);

      f32x4 a[4];
      #pragma unroll
      for (int rt = 0; rt < 4; ++rt) a[rt] = xvv[rt];   // acc init = x2
      #pragma unroll
      for (int rt = 0; rt < 4; ++rt) {
        a[rt] = __builtin_amdgcn_mfma_f32_16x16x32_bf16(afrag[0][rt], bfr0, a[rt], 0, 0, 0);
        a[rt] = __builtin_amdgcn_mfma_f32_16x16x32_bf16(afrag[1][rt], bfr1, a[rt], 0, 0, 0);
        a[rt] = __builtin_amdgcn_mfma_f32_16x16x32_bf16(afrag[2][rt], bfr2, a[rt], 0, 0, 0);
        a[rt] = __builtin_amdgcn_mfma_f32_16x16x32_bf16(afrag[3][rt], bfr3, a[rt], 0, 0, 0);
      }
      float cm = FINF;
      #pragma unroll
      for (int rt = 0; rt < 4; ++rt) {
        #pragma unroll
        for (int r = 0; r < 4; ++r) {
          float s = a[rt][r] + yv;             // = x2_i + y2_j - 2<x,y>
          rmin2[rt][r] = fminf(rmin2[rt][r], s);
          cm = fminf(cm, s);
        }
      }
      // cross-row (quad) reduce, then one LDS atomic per col (banks distinct)
      cm = fminf(cm, __shfl_xor(cm, 16, 64));
      cm = fminf(cm, __shfl_xor(cm, 32, 64));
      if (lane < 16) atomicMin(&cminS[c0 + ct * 16 + lane], __float_as_uint(cm));
    }
  }

  __syncthreads();   // all waves' cminS atomics done
  {
    float v0 = __uint_as_float(cminS[tid]);
    float v1 = __uint_as_float(cminS[tid + 256]);
    size_t cbase = (size_t)xg * (B_ * M_) + (size_t)b * M_ + mc0;
    colpart[cbase + tid]       = v0;
    colpart[cbase + tid + 256] = v1;
  }

  // Row mins over this chunk: reduce across 16 col-lanes (once, at the end).
  #pragma unroll
  for (int rt = 0; rt < 4; ++rt) {
    #pragma unroll
    for (int r = 0; r < 4; ++r) {
      float v = rmin2[rt][r];
      v = fminf(v, __shfl_xor(v, 1, 64));
      v = fminf(v, __shfl_xor(v, 2, 64));
      v = fminf(v, __shfl_xor(v, 4, 64));
      v = fminf(v, __shfl_xor(v, 8, 64));
      if (l15 == 0)
        rowpart[(size_t)chunk * (B_ * N_) + (size_t)b * N_ + n0 + wave * 64 + rt * 16 + quad * 4 + r] = v;
    }
  }
}

// Pass 3: reduce partials (min over chunks/x-groups), sqrt, sum, atomicAdd
// the block's contribution to the final scalar (d_out pre-zeroed).
__global__ __launch_bounds__(256) void pass3_final(
    const float* __restrict__ rowpart, const float* __restrict__ colpart,
    float* __restrict__ out)
{
  const int BN = B_ * N_;
  float s1 = 0.0f, s2 = 0.0f;
  for (int i = blockIdx.x * 256 + threadIdx.x; i < BN; i += 64 * 256) {
    float r = rowpart[i];
    #pragma unroll
    for (int c = 1; c < CHUNKS; ++c) r = fminf(r, rowpart[c * BN + i]);
    s1 += sqrtf(fmaxf(r, 0.0f));
    float m = colpart[i];
    #pragma unroll
    for (int g = 1; g < XG; ++g) m = fminf(m, colpart[g * BN + i]);
    s2 += sqrtf(fmaxf(m, 0.0f));
  }
  float s = s1 + s2;
  #pragma unroll
  for (int m = 1; m < 64; m <<= 1) s += __shfl_xor(s, m, 64);
  __shared__ float r1[4];
  int wave = threadIdx.x >> 6, lane = threadIdx.x & 63;
  if (lane == 0) r1[wave] = s;
  __syncthreads();
  if (threadIdx.x == 0)
    atomicAdd(out, (r1[0] + r1[1] + r1[2] + r1[3]) / (float)(B_ * N_));
}

extern "C" void kernel_launch(void* const* d_in, const int* in_sizes, int n_in,
                              void* d_out, int out_size, void* d_ws, size_t ws_size,
                              hipStream_t stream)
{
  const float* x = (const float*)d_in[0];
  const float* y = (const float*)d_in[1];
  char* ws = (char*)d_ws;

  unsigned short* xb = (unsigned short*)(ws);
  unsigned short* yb = (unsigned short*)(ws + (8u << 20));
  float* x2      = (float*)(ws + (16u << 20));
  float* y2      = (float*)(ws + (16u << 20) + (1u << 17));
  float* rowpart = (float*)(ws + (16u << 20) + (2u << 17));    // 8*B*N floats = 1 MB
  float* colpart = (float*)(ws + (16u << 20) + (10u << 17));   // 16*B*M floats = 2 MB
  float* outf = (float*)d_out;

  hipMemsetAsync(outf, 0, sizeof(float), stream);  // atomicAdd target

  pass1_prep<<<(B_ * N_) / 4, 256, 0, stream>>>(x, y, xb, yb, x2, y2);

  pass2_tile<<<B_ * XG * CHUNKS, 256, 0, stream>>>(xb, yb, x2, y2, rowpart, colpart);

  pass3_final<<<64, 256, 0, stream>>>(rowpart, colpart, outf);
}